// Round 1
// baseline (214.234 us; speedup 1.0000x reference)
//
#include <hip/hip_runtime.h>
#include <stdint.h>

#define Bz 32
#define Nz 4096
#define Lz 512
#define Dz 256
#define Mz (Bz*Nz)   // 131072 rows

typedef __attribute__((ext_vector_type(8))) short bf16x8;
typedef __attribute__((ext_vector_type(4))) float f32x4;

__device__ __forceinline__ uint32_t f2bf(float f) {
    union { float f; uint32_t u; } v; v.f = f;
    uint32_t u = v.u;
    u += 0x7FFFu + ((u >> 16) & 1u);   // RNE
    return u >> 16;
}

// ---------------------------------------------------------------------------
// Kernel 0: pack [Wa | Wb] (each 512x256 fp32, row-major K x D) into bf16
// MFMA-B-fragment order: block(ctile,ktile) of 64 lanes x 8 bf16, where
// lane l holds W[k = ktile*32 + (l>>4)*8 + j][col = ctile*16 + (l&15)].
// 32 ctiles (cols 0..511 = [a cols | g cols]) x 16 ktiles.
// ---------------------------------------------------------------------------
__global__ void pack_w(const float* __restrict__ Wa, const float* __restrict__ Wb,
                       unsigned short* __restrict__ packed)
{
    int tid = blockIdx.x * blockDim.x + threadIdx.x;   // 0..32767
    int ct   = tid >> 10;        // 0..31
    int kt   = (tid >> 6) & 15;  // 0..15
    int lane = tid & 63;
    int k0  = kt * 32 + ((lane >> 4) << 3);
    int col = ct * 16 + (lane & 15);
    const float* W = (col < 256) ? Wa : Wb;
    int c = col & 255;
    bf16x8 v;
    #pragma unroll
    for (int j = 0; j < 8; ++j) v[j] = (short)f2bf(W[(k0 + j) * 256 + c]);
    *(bf16x8*)(&packed[(size_t)tid * 8]) = v;
}

// ---------------------------------------------------------------------------
// Kernel 1: fused  scores = (tanh(xWa+ba) * sigmoid(xWb+bb)) . Wc + bc
// Also writes the exact fp32 copy of x to d_out (output 1) while staging.
// Block = 512 threads (8 waves), BM = 64 rows, full K=512, full 512 cols.
// Wave w owns a-cols [w*32, w*32+32) and matching g-cols [256+w*32, ...).
// ---------------------------------------------------------------------------
__global__ __launch_bounds__(512, 4) void fused_scores(
    const float* __restrict__ x, const unsigned short* __restrict__ packedW,
    const float* __restrict__ ba, const float* __restrict__ bb,
    const float* __restrict__ Wc, const float* __restrict__ bc,
    float* __restrict__ xcopy, float* __restrict__ scores)
{
    __shared__ unsigned short xlds[64 * Lz];   // 64 KiB, XOR-swizzled bf16
    __shared__ float spart[8][64];

    const int wg   = blockIdx.x;       // 0..2047
    const int row0 = wg * 64;
    const int t    = threadIdx.x;

    // ---- stage x (fp32 -> bf16 LDS) + write-through fp32 copy to d_out ----
    const float4* xsrc = (const float4*)(x      + (size_t)row0 * Lz);
    float4*       xdst = (float4*)      (xcopy  + (size_t)row0 * Lz);
    #pragma unroll
    for (int i = 0; i < 16; ++i) {
        int lin = i * 512 + t;            // float4 index, 128 per row
        float4 v = xsrc[lin];
        xdst[lin] = v;                    // exact passthrough
        int r  = lin >> 7;
        int kk = (lin & 127) << 2;        // k in floats
        uint32_t off = (uint32_t)(r * 1024 + kk * 2);
        off ^= (uint32_t)((r & 7) << 4);  // 16B-granule XOR swizzle
        uint32_t lo = f2bf(v.x) | (f2bf(v.y) << 16);
        uint32_t hi = f2bf(v.z) | (f2bf(v.w) << 16);
        *(uint2*)((char*)xlds + off) = make_uint2(lo, hi);
    }
    __syncthreads();

    const int wave = t >> 6;
    const int lane = t & 63;
    const int lrow = lane & 15;
    const int lkb  = (lane >> 4) << 3;    // 0,8,16,24 : k-base within ktile

    f32x4 acc[4][4];
    #pragma unroll
    for (int a = 0; a < 4; ++a)
        #pragma unroll
        for (int b = 0; b < 4; ++b)
            acc[a][b] = (f32x4){0.f, 0.f, 0.f, 0.f};

    // B-fragment pointers: this wave's 4 col-tiles (2 a-tiles, 2 g-tiles)
    const bf16x8* bp0 = (const bf16x8*)packedW;
    const bf16x8* bp[4];
    bp[0] = bp0 + (size_t)((2 * wave)      * 16) * 64 + lane;
    bp[1] = bp0 + (size_t)((2 * wave + 1)  * 16) * 64 + lane;
    bp[2] = bp0 + (size_t)((16 + 2 * wave) * 16) * 64 + lane;
    bp[3] = bp0 + (size_t)((17 + 2 * wave) * 16) * 64 + lane;

    #pragma unroll 2
    for (int kt = 0; kt < 16; ++kt) {
        bf16x8 av[4], bv[4];
        #pragma unroll
        for (int rf = 0; rf < 4; ++rf) {
            int r = rf * 16 + lrow;
            uint32_t off = (uint32_t)(r * 1024 + (kt * 32 + lkb) * 2);
            off ^= (uint32_t)((r & 7) << 4);
            av[rf] = *(const bf16x8*)((const char*)xlds + off);   // ds_read_b128
        }
        #pragma unroll
        for (int cf = 0; cf < 4; ++cf) bv[cf] = bp[cf][kt * 64];  // 16B from L2
        #pragma unroll
        for (int rf = 0; rf < 4; ++rf)
            #pragma unroll
            for (int cf = 0; cf < 4; ++cf)
                acc[rf][cf] = __builtin_amdgcn_mfma_f32_16x16x32_bf16(
                                  av[rf], bv[cf], acc[rf][cf], 0, 0, 0);
    }

    // ---- epilogue: bias + tanh*sigmoid, dot with Wc, per-row reduce ----
    // C/D layout: col = lane&15, row = rf*16 + (lane>>4)*4 + reg.
    // cf 0/1 are a-cols d0/d1; cf 2/3 are g-cols for the SAME d0/d1.
    const int d0 = wave * 32 + lrow;
    const int d1 = d0 + 16;
    const float ba0 = ba[d0], ba1 = ba[d1];
    const float bb0 = bb[d0], bb1 = bb[d1];
    const float wc0 = Wc[d0], wc1 = Wc[d1];

    #pragma unroll
    for (int rf = 0; rf < 4; ++rf) {
        #pragma unroll
        for (int r = 0; r < 4; ++r) {
            float pa0 = acc[rf][0][r] + ba0;
            float pa1 = acc[rf][1][r] + ba1;
            float pg0 = acc[rf][2][r] + bb0;
            float pg1 = acc[rf][3][r] + bb1;
            float e0 = __expf(-2.f * pa0);
            float e1 = __expf(-2.f * pa1);
            float a0 = (1.f - e0) / (1.f + e0);           // tanh
            float a1 = (1.f - e1) / (1.f + e1);
            float g0 = 1.f / (1.f + __expf(-pg0));        // sigmoid
            float g1 = 1.f / (1.f + __expf(-pg1));
            float p = a0 * g0 * wc0 + a1 * g1 * wc1;
            p += __shfl_xor(p, 1);
            p += __shfl_xor(p, 2);
            p += __shfl_xor(p, 4);
            p += __shfl_xor(p, 8);
            if (lrow == 0)
                spart[wave][rf * 16 + ((lane >> 4) << 2) + r] = p;
        }
    }
    __syncthreads();
    if (t < 64) {
        float s = bc[0];
        #pragma unroll
        for (int w = 0; w < 8; ++w) s += spart[w][t];
        scores[row0 + t] = s;   // raw scores; kernel 2 softmaxes in place
    }
}

// ---------------------------------------------------------------------------
// Kernel 2: per-batch softmax over N=4096, in place in d_out's A region.
// ---------------------------------------------------------------------------
__global__ __launch_bounds__(512) void softmax_rows(float* __restrict__ A)
{
    const int b = blockIdx.x;
    const int t = threadIdx.x;
    float* s = A + (size_t)b * Nz;
    float v[8];
    float m = -3.4e38f;
    #pragma unroll
    for (int i = 0; i < 8; ++i) { v[i] = s[t + i * 512]; m = fmaxf(m, v[i]); }
    #pragma unroll
    for (int o = 32; o; o >>= 1) m = fmaxf(m, __shfl_xor(m, o));
    __shared__ float redm[8], reds[8];
    const int wave = t >> 6, lane = t & 63;
    if (lane == 0) redm[wave] = m;
    __syncthreads();
    float M = redm[0];
    #pragma unroll
    for (int w = 1; w < 8; ++w) M = fmaxf(M, redm[w]);
    float sum = 0.f;
    #pragma unroll
    for (int i = 0; i < 8; ++i) { v[i] = __expf(v[i] - M); sum += v[i]; }
    #pragma unroll
    for (int o = 32; o; o >>= 1) sum += __shfl_xor(sum, o);
    if (lane == 0) reds[wave] = sum;
    __syncthreads();
    float tot = 0.f;
    #pragma unroll
    for (int w = 0; w < 8; ++w) tot += reds[w];
    float inv = 1.f / tot;
    #pragma unroll
    for (int i = 0; i < 8; ++i) s[t + i * 512] = v[i] * inv;
}

// ---------------------------------------------------------------------------
// Kernel 3: pooled partials.  grid = (b, nchunk of 256), block = 256.
// pooled[b,l] = sum_n A[b,n] * x[b,n,l]   (fp32 exact path)
// ---------------------------------------------------------------------------
__global__ __launch_bounds__(256) void pool_part(
    const float* __restrict__ x, const float* __restrict__ A,
    float* __restrict__ part)
{
    const int b  = blockIdx.x >> 4;
    const int ch = blockIdx.x & 15;
    const int t  = threadIdx.x;
    const int n0 = ch * 256;
    __shared__ float As[256];
    As[t] = A[(size_t)b * Nz + n0 + t];
    __syncthreads();
    const float2* xp = (const float2*)(x + ((size_t)b * Nz + n0) * Lz) + t;
    float a0 = 0.f, a1 = 0.f;
    #pragma unroll 4
    for (int n = 0; n < 256; ++n) {
        float  w  = As[n];
        float2 xv = xp[(size_t)n * 256];
        a0 += w * xv.x;
        a1 += w * xv.y;
    }
    float* pp = part + (size_t)blockIdx.x * 512;
    pp[2 * t]     = a0;
    pp[2 * t + 1] = a1;
}

// Kernel 4: reduce 16 partials -> pooled (32 x 512)
__global__ __launch_bounds__(256) void pool_reduce(
    const float* __restrict__ part, float* __restrict__ pooled)
{
    int idx = blockIdx.x * 256 + threadIdx.x;   // 0..16383
    int b = idx >> 9, l = idx & 511;
    float s = 0.f;
    #pragma unroll
    for (int c = 0; c < 16; ++c) s += part[((size_t)(b * 16 + c)) * 512 + l];
    pooled[idx] = s;
}

// ---------------------------------------------------------------------------
extern "C" void kernel_launch(void* const* d_in, const int* in_sizes, int n_in,
                              void* d_out, int out_size, void* d_ws, size_t ws_size,
                              hipStream_t stream)
{
    const float* x  = (const float*)d_in[0];
    const float* Wa = (const float*)d_in[1];
    const float* ba = (const float*)d_in[2];
    const float* Wb = (const float*)d_in[3];
    const float* bb = (const float*)d_in[4];
    const float* Wc = (const float*)d_in[5];
    const float* bc = (const float*)d_in[6];

    float* out    = (float*)d_out;
    float* A      = out;                           // B*N            = 131072
    float* xcopy  = out + (size_t)Mz;              // B*N*L          = 67108864
    float* pooled = xcopy + (size_t)Mz * Lz;       // B*L            = 16384

    unsigned short* packed = (unsigned short*)d_ws;              // 512 KiB
    float* part = (float*)((char*)d_ws + 512 * 1024);            // 32*16*512*4 = 1 MiB

    pack_w      <<<128, 256, 0, stream>>>(Wa, Wb, packed);
    fused_scores<<<Mz / 64, 512, 0, stream>>>(x, packed, ba, bb, Wc, bc, xcopy, A);
    softmax_rows<<<Bz, 512, 0, stream>>>(A);
    pool_part   <<<Bz * 16, 256, 0, stream>>>(x, A, part);
    pool_reduce <<<Mz * 0 + 64, 256, 0, stream>>>(part, pooled);
}